// Round 21
// baseline (149.720 us; speedup 1.0000x reference)
//
#include <hip/hip_runtime.h>

#define FDIM  256
#define H1D   256
#define H2D   128
#define BATCH 4096

typedef _Float16 half2v __attribute__((ext_vector_type(2)));

#define NHALF      64                        // n's per block
#define ROW_U32    68                        // 32 (A,C) u32 pairs + 4 pad (272 B, 16B-aligned)
#define NROWS      257
#define TABLE_U32  (NROWS * ROW_U32)         // 17,476
#define DLDS_BYTES (TABLE_U32 * 4)           // 69,904

#define XT_BYTES    ((size_t)FDIM * BATCH * 4)
#define W3H_BYTES   ((size_t)FDIM * 64 * 4)
#define PART_BYTES  ((size_t)512 * BATCH * 4)

#define SEG    8
#define SEGLEN 32

union U32H2 { unsigned u; half2v h; };
union H16U { _Float16 h; unsigned short u; };

// ---------------------------------------------------------------------------
// prep2: [0,256): x (B,F) f32 -> xT (F,B) f32 transpose.
//        [256,320): W3 f32 -> f16-pair packed w3h[f][64].
// ---------------------------------------------------------------------------
__global__ __launch_bounds__(256) void prep2(const float* __restrict__ x,
                                             const float* __restrict__ W3,
                                             float* __restrict__ xT,
                                             unsigned* __restrict__ w3h) {
    const int bid = blockIdx.x, tid = threadIdx.x;
    if (bid < 256) {
        __shared__ float tile[64][65];
        const int bt = bid >> 2, ft = bid & 3;
        const int tr = tid >> 2, c0 = (tid & 3) * 16;
#pragma unroll
        for (int j = 0; j < 4; ++j) {
            const float4 v = *(const float4*)(
                x + (size_t)(bt * 64 + tr) * FDIM + ft * 64 + c0 + j * 4);
            tile[tr][c0 + j * 4 + 0] = v.x;
            tile[tr][c0 + j * 4 + 1] = v.y;
            tile[tr][c0 + j * 4 + 2] = v.z;
            tile[tr][c0 + j * 4 + 3] = v.w;
        }
        __syncthreads();
        const int fr = tid >> 2, bb = (tid & 3) * 16;
#pragma unroll
        for (int j = 0; j < 4; ++j) {
            float4 o;
            o.x = tile[bb + j * 4 + 0][fr];
            o.y = tile[bb + j * 4 + 1][fr];
            o.z = tile[bb + j * 4 + 2][fr];
            o.w = tile[bb + j * 4 + 3][fr];
            *(float4*)(xT + (size_t)(ft * 64 + fr) * BATCH + bt * 64 + bb + j * 4) = o;
        }
    } else {
        const int idx = (bid - 256) * 256 + tid;    // 0..16383
        const int f = idx >> 6, p = idx & 63;
        U32H2 u;
        u.h[0] = (_Float16)W3[f * H2D + 2 * p];
        u.h[1] = (_Float16)W3[f * H2D + 2 * p + 1];
        w3h[f * 64 + p] = u.u;
    }
}

// ---------------------------------------------------------------------------
// Fused build+eval, n-split: block = (f, half), 512 blocks x 512 threads
// = 2 blocks/CU (table 69.9 KB + 4 KB static = 74 KB). Phases of the two
// co-resident blocks overlap (global-latency passes vs LDS-heavy eval).
// BUILD: rank-sort (3 barriers); Pass A (seg=wave, 64 n's, 1 W2 load/iter)
//   with scan scratch ALIASED into the unwritten table region (offsets ->
//   registers, barrier, then Pass B overwrites); Pass B shfl-paired uint2
//   row writes, rows = 32 interleaved (A,C) pairs, stride 68 u32.
// EVAL: E0 per-b search -> cpack (GLOBAL scratch; block-visible after
//   __syncthreads vmcnt drain; first in-kernel access is the store).
//   E1: 16-lane groups, 1 uint4 (b128) per b per lane, 2 fdot2, 4-shfl
//   reduce. launch_bounds(512,4): VGPR cap 128 -> E1 pipelines.
// ---------------------------------------------------------------------------
__global__ __launch_bounds__(512, 4) void coxnam_fused(
    const float* __restrict__ W1, const float* __restrict__ b1,
    const float* __restrict__ W2, const float* __restrict__ b2,
    const float* __restrict__ xT, const unsigned* __restrict__ w3h,
    unsigned* __restrict__ cpack, float* __restrict__ partial) {
    extern __shared__ unsigned rlds[];          // 17,476 u32
    __shared__ float w1_s[256], b1_s[256], ts2[256];
    __shared__ int id_s[256];
    // aliases into rlds (dead before Pass B writes rows)
    float* t_s  = (float*)rlds;                 // [0,256)
    unsigned* rk = rlds + 256;                  // [256,768)
    float* SA = (float*)(rlds);                 // [0,512)   (after rank phase)
    float* SC = SA + SEG * NHALF;               // [512,1024)
    float* BA = SC + SEG * NHALF;               // [1024,1536)
    float* BC = BA + SEG * NHALF;               // [1536,2048)

    const int fh = blockIdx.x;                  // 0..511
    const int f = fh >> 1, half = fh & 1;
    const int tid = threadIdx.x;

    if (tid < 256) {
        w1_s[tid] = W1[f * H1D + tid];
        b1_s[tid] = b1[f * H1D + tid];
    }
    __syncthreads();
    if (tid < 256) {
        const float w = w1_s[tid];
        t_s[tid] = (w != 0.f) ? (-b1_s[tid] / w) : __builtin_inff();
    }
    __syncthreads();
    // rank-sort: 2 threads/element x 128 compares
    {
        const int kq = tid >> 8, kk = tid & 255;
        const float tk = t_s[kk];
        int r = 0;
        const int k0 = kq * 128;
#pragma unroll 16
        for (int k2 = k0; k2 < k0 + 128; ++k2) {
            const float t2 = t_s[k2];
            r += (t2 < tk || (t2 == tk && k2 < kk)) ? 1 : 0;
        }
        rk[kq * 256 + kk] = (unsigned)r;
    }
    __syncthreads();
    if (tid < 256) {
        const int r = (int)(rk[tid] + rk[256 + tid]);
        ts2[r] = t_s[tid];
        id_s[r] = tid;
    }
    __syncthreads();

    const int seg = tid >> 6, n = tid & 63;     // wave == segment
    const int ng = half * NHALF + n;            // global n index
    const float* w2p = W2 + (size_t)f * H1D * H2D;

    // ---- Pass A: sorted walk; delta sums + base partials ----
    {
        float sa = 0.f, sc = 0.f, ba = 0.f, bc = 0.f;
#pragma unroll 8
        for (int ii = 0; ii < SEGLEN; ++ii) {
            const int kk = id_s[seg * SEGLEN + ii];
            const float ws = w1_s[kk], bs = b1_s[kk];
            const float w2s = w2p[kk * H2D + ng];
            if (ws < 0.f) { ba += ws * w2s; bc += bs * w2s; }
            else if (ws == 0.f && bs > 0.f) bc += bs * w2s;
            const float dA = (ws > 0.f) ? ws : ((ws < 0.f) ? -ws : 0.f);
            const float dC = (ws > 0.f) ? bs : ((ws < 0.f) ? -bs : 0.f);
            sa += dA * w2s;
            sc += dC * w2s;
        }
        SA[seg * NHALF + n] = sa; SC[seg * NHALF + n] = sc;
        BA[seg * NHALF + n] = ba; BC[seg * NHALF + n] = bc;
    }
    __syncthreads();

    // ---- offsets -> registers (before rows overwrite the scratch) ----
    float baseA = 0.f, baseC = b2[f * H2D + ng];
#pragma unroll
    for (int s = 0; s < SEG; ++s) {
        baseA += BA[s * NHALF + n];
        baseC += BC[s * NHALF + n];
    }
    float A = baseA, C = baseC;
    for (int s = 0; s < seg; ++s) {
        A += SA[s * NHALF + n];
        C += SC[s * NHALF + n];
    }
    __syncthreads();   // all scratch reads done; table writes may begin

    // ---- Pass B: walk segment, shfl-paired uint2 row writes ----
    {
        const int pr = n >> 1;
        const bool wr = ((n & 1) == 0);
        if (seg == 0) {
            H16U ah, ch;
            ah.h = (_Float16)baseA;
            ch.h = (_Float16)baseC;
            const unsigned ao = __shfl_xor((int)(unsigned)ah.u, 1);
            const unsigned co = __shfl_xor((int)(unsigned)ch.u, 1);
            if (wr) {
                uint2 v;
                v.x = (unsigned)ah.u | (ao << 16);
                v.y = (unsigned)ch.u | (co << 16);
                *(uint2*)(rlds + pr * 2) = v;
            }
        }
#pragma unroll 8
        for (int ii = 0; ii < SEGLEN; ++ii) {
            const int i = seg * SEGLEN + ii + 1;    // rows 1..256
            const int kk = id_s[i - 1];
            const float ws = w1_s[kk], bs = b1_s[kk];
            const float w2s = w2p[kk * H2D + ng];
            const float dA = (ws > 0.f) ? ws : ((ws < 0.f) ? -ws : 0.f);
            const float dC = (ws > 0.f) ? bs : ((ws < 0.f) ? -bs : 0.f);
            A += dA * w2s;
            C += dC * w2s;
            H16U ah, ch;
            ah.h = (_Float16)A;
            ch.h = (_Float16)C;
            const unsigned ao = __shfl_xor((int)(unsigned)ah.u, 1);
            const unsigned co = __shfl_xor((int)(unsigned)ch.u, 1);
            if (wr) {
                uint2 v;
                v.x = (unsigned)ah.u | (ao << 16);
                v.y = (unsigned)ch.u | (co << 16);
                *(uint2*)(rlds + i * ROW_U32 + pr * 2) = v;
            }
        }
    }

    // ---- E0: per-b interval search -> cpack (global, block-local use) ----
    unsigned* cpk = cpack + (size_t)fh * BATCH;
#pragma unroll
    for (int rd = 0; rd < 8; ++rd) {
        const int b = rd * 512 + tid;
        const float xv = xT[(size_t)f * BATCH + b];
        int c = 0;
#pragma unroll
        for (int s = 256; s >= 1; s >>= 1) {
            const int m = c + s;
            if (m <= 256 && ts2[m - 1] <= xv) c = m;
        }
        H16U hx;
        hx.h = (_Float16)xv;
        cpk[b] = (unsigned)c | ((unsigned)hx.u << 16);
    }
    __syncthreads();   // drains stores (vmcnt) + rows visible

    // ---- E1: 16-lane groups, 1 b128 per b per lane ----
    const int grp = tid >> 4, gl = tid & 15;    // 32 groups
    const uint2 w3q = *(const uint2*)(w3h + f * 64 + half * 32 + 2 * gl);
    const half2v z2 = {(_Float16)0.f, (_Float16)0.f};
#pragma unroll 4
    for (int p = 0; p < 128; ++p) {
        const int b = p * 32 + grp;
        const unsigned cinfo = cpk[b];
        const unsigned c = cinfo & 0xffffu;
        U32H2 xv2;
        xv2.u = (cinfo >> 16) | (cinfo & 0xffff0000u);
        const uint4 v = *(const uint4*)(rlds + c * ROW_U32 + 4 * gl);
        U32H2 a0, c0v, a1, c1v, w30, w31;
        a0.u = v.x; c0v.u = v.y; a1.u = v.z; c1v.u = v.w;
        w30.u = w3q.x; w31.u = w3q.y;
        half2v h0 = xv2.h * a0.h + c0v.h;
        half2v h1 = xv2.h * a1.h + c1v.h;
        h0 = __builtin_elementwise_max(h0, z2);
        h1 = __builtin_elementwise_max(h1, z2);
        float cacc = 0.f;
#if __has_builtin(__builtin_amdgcn_fdot2)
        cacc = __builtin_amdgcn_fdot2(h0, w30.h, cacc, false);
        cacc = __builtin_amdgcn_fdot2(h1, w31.h, cacc, false);
#else
        cacc += (float)h0[0] * (float)w30.h[0] + (float)h0[1] * (float)w30.h[1];
        cacc += (float)h1[0] * (float)w31.h[0] + (float)h1[1] * (float)w31.h[1];
#endif
        cacc += __shfl_xor(cacc, 1, 16);
        cacc += __shfl_xor(cacc, 2, 16);
        cacc += __shfl_xor(cacc, 4, 16);
        cacc += __shfl_xor(cacc, 8, 16);
        if (gl == 0) partial[(size_t)fh * BATCH + b] = cacc;
    }
}

// ---------------------------------------------------------------------------
// Final reduction over 512 partial rows + sum of b3.
// ---------------------------------------------------------------------------
__global__ __launch_bounds__(256) void reduce_out(const float* __restrict__ partial,
                                                  const float* __restrict__ b3,
                                                  float* __restrict__ out) {
    const int b = blockIdx.x * 256 + threadIdx.x;
    float v = 0.f;
#pragma unroll 8
    for (int p = 0; p < 512; ++p) v += partial[(size_t)p * BATCH + b];
    float sb3 = 0.f;
#pragma unroll 4
    for (int f4 = 0; f4 < FDIM; f4 += 4) {
        const float4 t = *(const float4*)(b3 + f4);
        sb3 += t.x + t.y + t.z + t.w;
    }
    out[b] = v + sb3;
}

extern "C" void kernel_launch(void* const* d_in, const int* in_sizes, int n_in,
                              void* d_out, int out_size, void* d_ws, size_t ws_size,
                              hipStream_t stream) {
    const float* x  = (const float*)d_in[0];
    const float* W1 = (const float*)d_in[1];
    const float* b1 = (const float*)d_in[2];
    const float* W2 = (const float*)d_in[3];
    const float* b2 = (const float*)d_in[4];
    const float* W3 = (const float*)d_in[5];
    const float* b3 = (const float*)d_in[6];

    float*    xT      = (float*)d_ws;
    unsigned* w3h     = (unsigned*)((char*)xT + XT_BYTES);
    float*    partial = (float*)((char*)w3h + W3H_BYTES);
    unsigned* cpack   = (unsigned*)((char*)partial + PART_BYTES);
    const size_t need = XT_BYTES + W3H_BYTES + PART_BYTES + (size_t)512 * BATCH * 4;
    if (ws_size < need) return;  // insufficient scratch; fail visibly

    prep2<<<320, 256, 0, stream>>>(x, W3, xT, w3h);
    coxnam_fused<<<512, 512, DLDS_BYTES, stream>>>(W1, b1, W2, b2, xT, w3h,
                                                   cpack, partial);
    reduce_out<<<BATCH / 256, 256, 0, stream>>>(partial, b3, (float*)d_out);
}

// Round 23
// 69.546 us; speedup vs baseline: 2.1528x; 2.1528x over previous
//
#include <hip/hip_runtime.h>

#define FDIM  256
#define H1D   256
#define H2D   128
#define BATCH 4096

typedef _Float16 half2v __attribute__((ext_vector_type(2)));

#define ROW_U32    132                       // 64 (A,C) u32 pairs + 4 pad (16B-aligned rows)
#define NROWS      257
#define DLDS_U32   (NROWS * ROW_U32)         // 33,924
#define DLDS_BYTES (DLDS_U32 * 4)            // 135,696

#define XT_BYTES   ((size_t)FDIM * BATCH * 4)
#define W3H_BYTES  ((size_t)FDIM * 64 * 4)

#define SEG    8
#define SEGLEN 32

union U32H2 { unsigned u; half2v h; };
union H16U { _Float16 h; unsigned short u; };

// DPP helpers: cross-lane on the VALU pipe (not DS). bound_ctrl=true -> 0 fill.
#define DPP_ADD_F(v, ctrl)                                                   \
    ((v) + __int_as_float(__builtin_amdgcn_update_dpp(                       \
               0, __float_as_int(v), (ctrl), 0xf, 0xf, true)))
#define DPP_GET_I(x, ctrl)                                                   \
    __builtin_amdgcn_update_dpp(0, (int)(x), (ctrl), 0xf, 0xf, true)
// ctrl: quad_perm[1,0,3,2]=0xB1 (xor1), [2,3,0,1]=0x4E (xor2),
//       row_ror:4=0x124, row_ror:8=0x128 (rotation: total lands in ALL
//       lanes of the 16-row — row_shr would land it only in lanes 12-15,
//       which was round 22's correctness bug).

// ---------------------------------------------------------------------------
// prep2: [0,256): x (B,F) f32 -> xT (F,B) f32 transpose.
//        [256,320): W3 f32 -> f16-pair packed w3h[f][64].
// ---------------------------------------------------------------------------
__global__ __launch_bounds__(256) void prep2(const float* __restrict__ x,
                                             const float* __restrict__ W3,
                                             float* __restrict__ xT,
                                             unsigned* __restrict__ w3h) {
    const int bid = blockIdx.x, tid = threadIdx.x;
    if (bid < 256) {
        __shared__ float tile[64][65];
        const int bt = bid >> 2, ft = bid & 3;
        const int tr = tid >> 2, c0 = (tid & 3) * 16;
#pragma unroll
        for (int j = 0; j < 4; ++j) {
            const float4 v = *(const float4*)(
                x + (size_t)(bt * 64 + tr) * FDIM + ft * 64 + c0 + j * 4);
            tile[tr][c0 + j * 4 + 0] = v.x;
            tile[tr][c0 + j * 4 + 1] = v.y;
            tile[tr][c0 + j * 4 + 2] = v.z;
            tile[tr][c0 + j * 4 + 3] = v.w;
        }
        __syncthreads();
        const int fr = tid >> 2, bb = (tid & 3) * 16;
#pragma unroll
        for (int j = 0; j < 4; ++j) {
            float4 o;
            o.x = tile[bb + j * 4 + 0][fr];
            o.y = tile[bb + j * 4 + 1][fr];
            o.z = tile[bb + j * 4 + 2][fr];
            o.w = tile[bb + j * 4 + 3][fr];
            *(float4*)(xT + (size_t)(ft * 64 + fr) * BATCH + bt * 64 + bb + j * 4) = o;
        }
    } else {
        const int idx = (bid - 256) * 256 + tid;    // 0..16383
        const int f = idx >> 6, p = idx & 63;
        U32H2 u;
        u.h[0] = (_Float16)W3[f * H2D + 2 * p];
        u.h[1] = (_Float16)W3[f * H2D + 2 * p + 1];
        w3h[f * 64 + p] = u.u;
    }
}

// ---------------------------------------------------------------------------
// Fused build+eval (R20 champion + DS-pipe diet, DPP-ror fixed):
// BUILD: rank-sort (3 barriers); Pass A (sorted walk, base folded, 1 W2
//   load/iter); Pass B walk with DPP-paired (VALU) uint2 row writes.
// EVAL: E0 per-b search -> (c | f16(xv)<<16) in LDS scratch. E1: 16-lane
//   groups, 2x b128/p, 4 fdot2, then DPP reduce (quad_perm x2 + row_ror:4/8
//   — VALU pipe, replacing 4 ds_bpermute shuffles); 2-way p-unroll for ILP.
// ---------------------------------------------------------------------------
__global__ __launch_bounds__(1024) void coxnam_fused(
    const float* __restrict__ W1, const float* __restrict__ b1,
    const float* __restrict__ W2, const float* __restrict__ b2,
    const float* __restrict__ xT, const unsigned* __restrict__ w3h,
    float* __restrict__ partial) {
    extern __shared__ unsigned rlds[];          // 33,924 u32 = 132.5 KB
    __shared__ float t_s[256], w1_s[256], b1_s[256], ts2[256];
    __shared__ int id_s[256];
    __shared__ unsigned scratch[SEG * 128 * 4]; // 16 KB: ranks / SA..BC / c-pack
    float* SA = (float*)scratch;
    float* SC = SA + SEG * 128;
    float* BA = SC + SEG * 128;
    float* BC = BA + SEG * 128;
    const int f = blockIdx.x, tid = threadIdx.x;

    if (tid < 256) {
        const float w = W1[f * H1D + tid];
        const float bb = b1[f * H1D + tid];
        w1_s[tid] = w;
        b1_s[tid] = bb;
        t_s[tid] = (w != 0.f) ? (-bb / w) : __builtin_inff();
    }
    __syncthreads();

    // ---- rank-sort ----
    {
        const int kq = tid >> 8, kk = tid & 255;
        const float tk = t_s[kk];
        int r = 0;
        const int k0 = kq * 64;
#pragma unroll 16
        for (int k2 = k0; k2 < k0 + 64; ++k2) {
            const float t2 = t_s[k2];
            r += (t2 < tk || (t2 == tk && k2 < kk)) ? 1 : 0;
        }
        scratch[kq * 256 + kk] = (unsigned)r;
    }
    __syncthreads();
    if (tid < 256) {
        const int r = (int)(scratch[tid] + scratch[256 + tid] +
                            scratch[512 + tid] + scratch[768 + tid]);
        ts2[r] = t_s[tid];
        id_s[r] = tid;
    }
    __syncthreads();

    const int seg = tid >> 7, n = tid & 127;
    const float* w2p = W2 + (size_t)f * H1D * H2D;

    // ---- Pass A ----
    {
        float sa = 0.f, sc = 0.f, ba = 0.f, bc = 0.f;
#pragma unroll 8
        for (int ii = 0; ii < SEGLEN; ++ii) {
            const int kk = id_s[seg * SEGLEN + ii];
            const float ws = w1_s[kk], bs = b1_s[kk];
            const float w2s = w2p[kk * H2D + n];
            if (ws < 0.f) { ba += ws * w2s; bc += bs * w2s; }
            else if (ws == 0.f && bs > 0.f) bc += bs * w2s;
            const float dA = (ws > 0.f) ? ws : ((ws < 0.f) ? -ws : 0.f);
            const float dC = (ws > 0.f) ? bs : ((ws < 0.f) ? -bs : 0.f);
            sa += dA * w2s;
            sc += dC * w2s;
        }
        SA[seg * 128 + n] = sa; SC[seg * 128 + n] = sc;
        BA[seg * 128 + n] = ba; BC[seg * 128 + n] = bc;
    }
    __syncthreads();

    // ---- offsets + Pass B (DPP-paired uint2 writes) ----
    {
        float baseA = 0.f, baseC = b2[f * H2D + n];
#pragma unroll
        for (int s = 0; s < SEG; ++s) {
            baseA += BA[s * 128 + n];
            baseC += BC[s * 128 + n];
        }
        float A = baseA, C = baseC;
        for (int s = 0; s < seg; ++s) {
            A += SA[s * 128 + n];
            C += SC[s * 128 + n];
        }
        const int pr = n >> 1;
        const bool wr = ((n & 1) == 0);
        if (seg == 0) {
            H16U ah, ch;
            ah.h = (_Float16)baseA;
            ch.h = (_Float16)baseC;
            const unsigned ao = (unsigned)DPP_GET_I(ah.u, 0xB1);
            const unsigned co = (unsigned)DPP_GET_I(ch.u, 0xB1);
            if (wr) {
                uint2 v;
                v.x = (unsigned)ah.u | (ao << 16);
                v.y = (unsigned)ch.u | (co << 16);
                *(uint2*)(rlds + pr * 2) = v;
            }
        }
#pragma unroll 8
        for (int ii = 0; ii < SEGLEN; ++ii) {
            const int i = seg * SEGLEN + ii + 1;    // rows 1..256
            const int kk = id_s[i - 1];
            const float ws = w1_s[kk], bs = b1_s[kk];
            const float w2s = w2p[kk * H2D + n];
            const float dA = (ws > 0.f) ? ws : ((ws < 0.f) ? -ws : 0.f);
            const float dC = (ws > 0.f) ? bs : ((ws < 0.f) ? -bs : 0.f);
            A += dA * w2s;
            C += dC * w2s;
            H16U ah, ch;
            ah.h = (_Float16)A;
            ch.h = (_Float16)C;
            const unsigned ao = (unsigned)DPP_GET_I(ah.u, 0xB1);
            const unsigned co = (unsigned)DPP_GET_I(ch.u, 0xB1);
            if (wr) {
                uint2 v;
                v.x = (unsigned)ah.u | (ao << 16);
                v.y = (unsigned)ch.u | (co << 16);
                *(uint2*)(rlds + i * ROW_U32 + pr * 2) = v;
            }
        }
    }
    __syncthreads();   // rows done; scratch free for c-pack

    // ---- E0: per-b interval search, pack (c | f16(xv)<<16) ----
#pragma unroll
    for (int rd = 0; rd < 4; ++rd) {
        const int b = rd * 1024 + tid;
        const float xv = xT[(size_t)f * BATCH + b];
        int c = 0;
#pragma unroll
        for (int s = 256; s >= 1; s >>= 1) {
            const int m = c + s;
            if (m <= 256 && ts2[m - 1] <= xv) c = m;
        }
        H16U hx;
        hx.h = (_Float16)xv;
        scratch[b] = (unsigned)c | ((unsigned)hx.u << 16);
    }
    __syncthreads();

    // ---- E1: 16-lane groups; DS = 2 b128 + 1 scratch read per b;
    //      reduction on VALU via DPP (ror: total in all lanes, gl==0 valid);
    //      2-way p-unroll for load ILP ----
    const int grp = tid >> 4, gl = tid & 15;
    const unsigned* wp = w3h + f * 64;
    const uint2 w3q0 = *(const uint2*)(wp + 2 * gl);
    const uint2 w3q1 = *(const uint2*)(wp + 32 + 2 * gl);
    const half2v z2 = {(_Float16)0.f, (_Float16)0.f};
#pragma unroll 2
    for (int p = 0; p < 64; p += 2) {
        const int b0 = p * 64 + grp;
        const int b1i = (p + 1) * 64 + grp;
        const unsigned ci0 = scratch[b0];
        const unsigned ci1 = scratch[b1i];
        const unsigned* rp0 = rlds + (ci0 & 0xffffu) * ROW_U32;
        const unsigned* rp1 = rlds + (ci1 & 0xffffu) * ROW_U32;
        // issue all 4 b128 loads up front (ILP)
        const uint4 v00 = *(const uint4*)(rp0 + 4 * gl);
        const uint4 v01 = *(const uint4*)(rp0 + 4 * gl + 64);
        const uint4 v10 = *(const uint4*)(rp1 + 4 * gl);
        const uint4 v11 = *(const uint4*)(rp1 + 4 * gl + 64);
        U32H2 xv0, xv1;
        xv0.u = (ci0 >> 16) | (ci0 & 0xffff0000u);
        xv1.u = (ci1 >> 16) | (ci1 & 0xffff0000u);
        float c0a = 0.f, c1a = 0.f;
        {
            U32H2 a0, cc0, a1, cc1, w30, w31;
            a0.u = v00.x; cc0.u = v00.y; a1.u = v00.z; cc1.u = v00.w;
            w30.u = w3q0.x; w31.u = w3q0.y;
            half2v h0 = __builtin_elementwise_max(xv0.h * a0.h + cc0.h, z2);
            half2v h1 = __builtin_elementwise_max(xv0.h * a1.h + cc1.h, z2);
            c0a = __builtin_amdgcn_fdot2(h0, w30.h, c0a, false);
            c0a = __builtin_amdgcn_fdot2(h1, w31.h, c0a, false);
            a0.u = v01.x; cc0.u = v01.y; a1.u = v01.z; cc1.u = v01.w;
            w30.u = w3q1.x; w31.u = w3q1.y;
            h0 = __builtin_elementwise_max(xv0.h * a0.h + cc0.h, z2);
            h1 = __builtin_elementwise_max(xv0.h * a1.h + cc1.h, z2);
            c0a = __builtin_amdgcn_fdot2(h0, w30.h, c0a, false);
            c0a = __builtin_amdgcn_fdot2(h1, w31.h, c0a, false);
        }
        {
            U32H2 a0, cc0, a1, cc1, w30, w31;
            a0.u = v10.x; cc0.u = v10.y; a1.u = v10.z; cc1.u = v10.w;
            w30.u = w3q0.x; w31.u = w3q0.y;
            half2v h0 = __builtin_elementwise_max(xv1.h * a0.h + cc0.h, z2);
            half2v h1 = __builtin_elementwise_max(xv1.h * a1.h + cc1.h, z2);
            c1a = __builtin_amdgcn_fdot2(h0, w30.h, c1a, false);
            c1a = __builtin_amdgcn_fdot2(h1, w31.h, c1a, false);
            a0.u = v11.x; cc0.u = v11.y; a1.u = v11.z; cc1.u = v11.w;
            w30.u = w3q1.x; w31.u = w3q1.y;
            h0 = __builtin_elementwise_max(xv1.h * a0.h + cc0.h, z2);
            h1 = __builtin_elementwise_max(xv1.h * a1.h + cc1.h, z2);
            c1a = __builtin_amdgcn_fdot2(h0, w30.h, c1a, false);
            c1a = __builtin_amdgcn_fdot2(h1, w31.h, c1a, false);
        }
        // DPP reduce within each 16-lane row (VALU pipe); rotation variant:
        // after quad sums, ror:4 + ror:8 put the FULL total in every lane.
        c0a = DPP_ADD_F(c0a, 0xB1);
        c0a = DPP_ADD_F(c0a, 0x4E);
        c0a = DPP_ADD_F(c0a, 0x124);
        c0a = DPP_ADD_F(c0a, 0x128);
        c1a = DPP_ADD_F(c1a, 0xB1);
        c1a = DPP_ADD_F(c1a, 0x4E);
        c1a = DPP_ADD_F(c1a, 0x124);
        c1a = DPP_ADD_F(c1a, 0x128);
        if (gl == 0) {
            partial[(size_t)f * BATCH + b0] = c0a;
            partial[(size_t)f * BATCH + b1i] = c1a;
        }
    }
}

// ---------------------------------------------------------------------------
// Final reduction over 256 per-feature partials + sum of b3.
// ---------------------------------------------------------------------------
__global__ __launch_bounds__(256) void reduce_out(const float* __restrict__ partial,
                                                  const float* __restrict__ b3,
                                                  float* __restrict__ out) {
    const int b = blockIdx.x * 256 + threadIdx.x;
    float v = 0.f;
    for (int p = 0; p < FDIM; ++p) v += partial[(size_t)p * BATCH + b];
    float sb3 = 0.f;
#pragma unroll 4
    for (int f4 = 0; f4 < FDIM; f4 += 4) {
        const float4 t = *(const float4*)(b3 + f4);
        sb3 += t.x + t.y + t.z + t.w;
    }
    out[b] = v + sb3;
}

extern "C" void kernel_launch(void* const* d_in, const int* in_sizes, int n_in,
                              void* d_out, int out_size, void* d_ws, size_t ws_size,
                              hipStream_t stream) {
    const float* x  = (const float*)d_in[0];
    const float* W1 = (const float*)d_in[1];
    const float* b1 = (const float*)d_in[2];
    const float* W2 = (const float*)d_in[3];
    const float* b2 = (const float*)d_in[4];
    const float* W3 = (const float*)d_in[5];
    const float* b3 = (const float*)d_in[6];

    float*    xT      = (float*)d_ws;
    unsigned* w3h     = (unsigned*)((char*)xT + XT_BYTES);
    float*    partial = (float*)((char*)w3h + W3H_BYTES);
    const size_t need = XT_BYTES + W3H_BYTES + (size_t)FDIM * BATCH * 4;
    if (ws_size < need) return;  // insufficient scratch; fail visibly

    prep2<<<320, 256, 0, stream>>>(x, W3, xT, w3h);
    coxnam_fused<<<256, 1024, DLDS_BYTES, stream>>>(W1, b1, W2, b2, xT, w3h,
                                                    partial);
    reduce_out<<<BATCH / 256, 256, 0, stream>>>(partial, b3, (float*)d_out);
}